// Round 5
// baseline (583.549 us; speedup 1.0000x reference)
//
#include <hip/hip_runtime.h>

// Problem constants (GRID=192, ISO=0)
#define GN 192           // grid points per axis
#define CN 193           // cells per axis (GN+1)
#define CN2 (CN * CN)    // 37249

// Output layout (float32 elements), in reference return order:
//   verts : CN^3 * 3
//   vmask : CN^3
//   quads : 3 * CN*GN*GN * 4
//   qmask : 3 * CN*GN*GN
#define NV        ((size_t)CN * CN * CN)                  // 7,189,057
#define OFF_VMASK ((size_t)(NV * 3))                      // 21,567,171
#define OFF_QUADS ((size_t)(OFF_VMASK + NV))              // 28,756,228 (x4 bytes: 16B-aligned)
#define QSEG      ((size_t)CN * GN * GN)                  // 7,114,752 rows per segment
#define OFF_QMASK ((size_t)(OFF_QUADS + 3 * QSEG * 4))

typedef float f4 __attribute__((ext_vector_type(4)));

// A/B vs round 4: PLAIN stores instead of non-temporal. Three different
// NT-store kernels all pinned at ~2.3-2.4 TB/s effective; the harness's
// plain-store fill hits 6.2 TB/s on the same buffer. Theory: gfx950 `nt`
// bypasses L2 write-combining; plain write-allocate is the fast path.
__device__ __forceinline__ void nts(float* p, float v) { *p = v; }
__device__ __forceinline__ void nts4(f4* p, f4 v) { *p = v; }

// ========================= kernel Q: quads (pure index math) ==============
// QSEG = 6948 * 1024 exactly -> each block of 1024 rows lies in ONE segment.
// Lane-contiguous f4 stores: each instruction writes 4KB of full 64B lines.
#define QBLK 6948

__global__ __launch_bounds__(256) void dmc_quads(float* __restrict__ out) {
    f4* const quads = (f4*)(out + OFF_QUADS);
    const unsigned b = blockIdx.x;
    const unsigned seg = b / QBLK;                       // 0,1,2 (uniform per block)
    const unsigned r0 = (b - seg * QBLK) * 1024u + threadIdx.x;
    float d0, d1, d2, d3;
    if (seg == 0)      { d0 = 0.f;      d1 = 193.f;  d2 = 194.f; d3 = 1.f; }
    else if (seg == 1) { d0 = -37249.f; d1 = 0.f;    d2 = 1.f;   d3 = -37248.f; }
    else               { d0 = -37442.f; d1 = -193.f; d2 = 0.f;   d3 = -37249.f; }
#pragma unroll
    for (int s = 0; s < 4; ++s) {
        const unsigned r = r0 + 256u * s;
        unsigned i, j, k, t;
        if (seg == 0)      { k = r % GN; t = r / GN; j = t % GN; i = t / GN; }
        else if (seg == 1) { k = r % GN; t = r / GN; j = t % CN; i = t / CN + 1; }
        else               { k = r % CN; t = r / CN; j = t % GN + 1; i = t / GN + 1; }
        const float flin = (float)((i * CN + j) * CN + k);   // cell id, exact (<2^24)
        nts4(quads + seg * QSEG + r, (f4){flin + d0, flin + d1, flin + d2, flin + d3});
    }
}

// ========================= kernel V: verts/vmask/qmask ====================
// 1 cell/thread, block = 256 consecutive lin. For each quad segment, row
// index r is contiguous & monotone in lin over the segment's valid cells,
// so a block's qmask output is the contiguous window [rmin, rmax], computed
// analytically from the (uniform) first/last lin of the block. Threads deposit
// values in LDS at slot (r - rmin); cooperative contiguous dword stores.
__global__ __launch_bounds__(256) void dmc_verts(const float* __restrict__ g,
                                                 float* __restrict__ out) {
    __shared__ __align__(16) float vlds[256 * 3];
    __shared__ float qAl[256], qBl[256], qCl[256];

    const int tid = threadIdx.x;
    const size_t lin0 = (size_t)blockIdx.x * 256;
    const size_t lin = lin0 + tid;
    const bool valid = lin < NV;
    const int linI = valid ? (int)lin : (int)(NV - 1);
    const int k = linI % CN;
    const int t2 = linI / CN;
    const int j = t2 % CN;
    const int i = t2 / CN;

    // ---- uniform qmask windows from block's first/last lin ----
    const int L0 = (int)lin0;
    const int L1 = (int)((lin0 + 255 < NV) ? (lin0 + 255) : (NV - 1));
    const int k0 = L0 % CN, u0 = L0 / CN, j0 = u0 % CN, i0 = u0 / CN;
    const int k1 = L1 % CN, u1 = L1 / CN, j1 = u1 % CN, i1 = u1 / CN;

    int rminA, rmaxA, rminB, rmaxB, rminC, rmaxC;
    // segment A: valid j<192 && k<192; r = (i*192+j)*192+k
    { int a = i0, bb = j0, c = k0;
      if (bb == GN) { a++; bb = 0; c = 0; }
      else if (c == GN) { bb++; c = 0; if (bb == GN) { a++; bb = 0; } }
      rminA = (a * GN + bb) * GN + c; }
    { int a = i1, bb = j1, c = k1;
      if (bb == GN) { bb = GN - 1; c = GN - 1; }
      else if (c == GN) { c = GN - 1; }
      rmaxA = (a * GN + bb) * GN + c; }
    // segment B: valid i>=1 && k<192; r = ((i-1)*193+j)*192+k
    { int a = i0, bb = j0, c = k0;
      if (a == 0) { a = 1; bb = 0; c = 0; }
      else if (c == GN) { bb++; c = 0; if (bb == CN) { bb = 0; a++; } }
      rminB = ((a - 1) * CN + bb) * GN + c; }
    { int a = i1, bb = j1, c = k1;
      if (a == 0) rmaxB = -1;
      else { if (c == GN) c = GN - 1; rmaxB = ((a - 1) * CN + bb) * GN + c; } }
    // segment C: valid i>=1 && j>=1; r = ((i-1)*192+(j-1))*193+k
    { int a = i0, bb = j0, c = k0;
      if (a == 0) { a = 1; bb = 1; c = 0; }
      else if (bb == 0) { bb = 1; c = 0; }
      rminC = ((a - 1) * GN + (bb - 1)) * CN + c; }
    { int a = i1, bb = j1, c = k1;
      if (a == 0) rmaxC = -1;
      else if (bb == 0) { a--; rmaxC = (a == 0) ? -1 : ((a - 1) * GN + (GN - 1)) * CN + (CN - 1); }
      else rmaxC = ((a - 1) * GN + (bb - 1)) * CN + c; }
    int cntA = rmaxA - rminA + 1; if (cntA < 0) cntA = 0;
    int cntB = rmaxB - rminB + 1; if (cntB < 0) cntB = 0;
    int cntC = rmaxC - rminC + 1; if (cntC < 0) cntC = 0;

    // ---- branchless clamped corner loads (pad = iso+1 = 1.0) ----
    const int xm = (i >= 1) ? i - 1 : 0;
    const int xp = (i <= GN - 1) ? i : GN - 1;
    const int ym = (j >= 1) ? j - 1 : 0;
    const int yp = (j <= GN - 1) ? j : GN - 1;
    const int zm = (k >= 1) ? k - 1 : 0;
    const int zp = (k <= GN - 1) ? k : GN - 1;
    const bool xv0 = (i >= 1), xv1 = (i <= GN - 1);
    const bool yv0 = (j >= 1), yv1 = (j <= GN - 1);
    const bool zv0 = (k >= 1), zv1 = (k <= GN - 1);

    const float* b00 = g + ((size_t)xm * GN + ym) * GN;
    const float* b01 = g + ((size_t)xm * GN + yp) * GN;
    const float* b10 = g + ((size_t)xp * GN + ym) * GN;
    const float* b11 = g + ((size_t)xp * GN + yp) * GN;

    const float v000 = (xv0 & yv0 & zv0) ? b00[zm] : 1.0f;
    const float v001 = (xv0 & yv0 & zv1) ? b00[zp] : 1.0f;
    const float v010 = (xv0 & yv1 & zv0) ? b01[zm] : 1.0f;
    const float v011 = (xv0 & yv1 & zv1) ? b01[zp] : 1.0f;
    const float v100 = (xv1 & yv0 & zv0) ? b10[zm] : 1.0f;
    const float v101 = (xv1 & yv0 & zv1) ? b10[zp] : 1.0f;
    const float v110 = (xv1 & yv1 & zv0) ? b11[zm] : 1.0f;
    const float v111 = (xv1 & yv1 & zv1) ? b11[zp] : 1.0f;

    // ---- dual vertex: branchless 12-edge accumulation, Newton-refined rcp ----
    float sx = 0.f, sy = 0.f, sz = 0.f, cf = 0.f;
    auto acc = [&](float vA, float vB, int axis, float o1, float o2) {
        const bool cr = (vA < 0.f) != (vB < 0.f);
        const float m = cr ? 1.0f : 0.0f;
        const float d = cr ? (vB - vA) : 1.0f;      // safe operand (no inf/NaN)
        float r = __builtin_amdgcn_rcpf(d);
        r = r * (2.0f - d * r);                      // 1 Newton step
        const float t = cr ? (-vA * r) : 0.0f;
        if (axis == 0)      { sx += t;      sy += m * o1; sz += m * o2; }
        else if (axis == 1) { sx += m * o1; sy += t;      sz += m * o2; }
        else                { sx += m * o1; sy += m * o2; sz += t;      }
        cf += m;
    };
    acc(v000, v100, 0, 0.f, 0.f);
    acc(v010, v110, 0, 1.f, 0.f);
    acc(v001, v101, 0, 0.f, 1.f);
    acc(v011, v111, 0, 1.f, 1.f);
    acc(v000, v010, 1, 0.f, 0.f);
    acc(v100, v110, 1, 1.f, 0.f);
    acc(v001, v011, 1, 0.f, 1.f);
    acc(v101, v111, 1, 1.f, 1.f);
    acc(v000, v001, 2, 0.f, 0.f);
    acc(v100, v101, 2, 1.f, 0.f);
    acc(v010, v011, 2, 0.f, 1.f);
    acc(v110, v111, 2, 1.f, 1.f);

    const float cfm = fmaxf(cf, 1.0f);
    float rc = __builtin_amdgcn_rcpf(cfm);
    rc = rc * (2.0f - cfm * rc);
    const float inv191 = 1.0f / 191.0f;
    vlds[tid * 3 + 0] = ((float)i + sx * rc - 1.0f) * inv191;
    vlds[tid * 3 + 1] = ((float)j + sy * rc - 1.0f) * inv191;
    vlds[tid * 3 + 2] = ((float)k + sz * rc - 1.0f) * inv191;

    // vmask: per-thread dword, naturally contiguous (256B/instr = full lines)
    if (valid) nts(out + OFF_VMASK + lin, (cf > 0.f) ? 1.0f : 0.0f);

    // qmask values -> LDS at window slot
    if (valid) {
        if (j < GN && k < GN)
            qAl[(i * GN + j) * GN + k - rminA] = ((v011 < 0.f) != (v111 < 0.f)) ? 1.0f : 0.0f;
        if (i >= 1 && k < GN)
            qBl[((i - 1) * CN + j) * GN + k - rminB] = ((v001 < 0.f) != (v011 < 0.f)) ? 1.0f : 0.0f;
        if (i >= 1 && j >= 1)
            qCl[((i - 1) * GN + (j - 1)) * CN + k - rminC] = ((v000 < 0.f) != (v001 < 0.f)) ? 1.0f : 0.0f;
    }
    __syncthreads();

    // ---- cooperative coalesced stores ----
    const int nvalid = L1 - L0 + 1;
    const int nfl = 3 * nvalid;
    const int nf4 = nfl >> 2;
    if (tid < nf4)
        nts4((f4*)(out + lin0 * 3) + tid, ((const f4*)vlds)[tid]);   // 16B-aligned
    if (tid == nf4)
        for (int rr = nf4 * 4; rr < nfl; ++rr) nts(out + lin0 * 3 + rr, vlds[rr]);

    if (tid < cntA) nts(out + OFF_QMASK + (size_t)rminA + tid, qAl[tid]);
    if (tid < cntB) nts(out + OFF_QMASK + QSEG + (size_t)rminB + tid, qBl[tid]);
    if (tid < cntC) nts(out + OFF_QMASK + 2 * QSEG + (size_t)rminC + tid, qCl[tid]);
}

extern "C" void kernel_launch(void* const* d_in, const int* in_sizes, int n_in,
                              void* d_out, int out_size, void* d_ws, size_t ws_size,
                              hipStream_t stream) {
    const float* g = (const float*)d_in[0];
    float* out = (float*)d_out;
    const int nbV = (int)((NV + 255) / 256);   // 28083
    dmc_verts<<<dim3(nbV), dim3(256), 0, stream>>>(g, out);
    dmc_quads<<<dim3(3 * QBLK), dim3(256), 0, stream>>>(out);
}

// Round 6
// 571.772 us; speedup vs baseline: 1.0206x; 1.0206x over previous
//
#include <hip/hip_runtime.h>

// Problem constants (GRID=192, ISO=0)
#define GN 192           // grid points per axis
#define CN 193           // cells per axis (GN+1)
#define CN2 (CN * CN)    // 37249

// Output layout (float32 elements), in reference return order:
//   verts : CN^3 * 3
//   vmask : CN^3
//   quads : 3 * CN*GN*GN * 4
//   qmask : 3 * CN*GN*GN
#define NV        ((size_t)CN * CN * CN)                  // 7,189,057
#define OFF_VMASK ((size_t)(NV * 3))                      // 21,567,171
#define OFF_QUADS ((size_t)(OFF_VMASK + NV))              // 28,756,228 (x4 bytes: 16B-aligned)
#define QSEG      ((size_t)CN * GN * GN)                  // 7,114,752 rows per segment
#define OFF_QMASK ((size_t)(OFF_QUADS + 3 * QSEG * 4))

#define QBLK 6948                                         // quads blocks per segment
#define NQB  (3 * QBLK)                                   // 20844 quads-role blocks
#define NBV  ((unsigned)((NV + 255) / 256))               // 28083 verts-role blocks

typedef float f4 __attribute__((ext_vector_type(4)));

__device__ __forceinline__ void nts(float* p, float v) { __builtin_nontemporal_store(v, p); }
__device__ __forceinline__ void nts4(f4* p, f4 v) { __builtin_nontemporal_store(v, p); }

// ========================= quads role (pure index math) ===================
// QSEG = 6948 * 1024 exactly -> each block of 1024 rows lies in ONE segment.
__device__ __forceinline__ void quads_body(unsigned b, float* __restrict__ out) {
    f4* const quads = (f4*)(out + OFF_QUADS);
    const unsigned seg = b / QBLK;                       // 0,1,2 (uniform per block)
    const unsigned r0 = (b - seg * QBLK) * 1024u + threadIdx.x;
    float d0, d1, d2, d3;
    if (seg == 0)      { d0 = 0.f;      d1 = 193.f;  d2 = 194.f; d3 = 1.f; }
    else if (seg == 1) { d0 = -37249.f; d1 = 0.f;    d2 = 1.f;   d3 = -37248.f; }
    else               { d0 = -37442.f; d1 = -193.f; d2 = 0.f;   d3 = -37249.f; }
#pragma unroll
    for (int s = 0; s < 4; ++s) {
        const unsigned r = r0 + 256u * s;
        unsigned i, j, k, t;
        if (seg == 0)      { k = r % GN; t = r / GN; j = t % GN; i = t / GN; }
        else if (seg == 1) { k = r % GN; t = r / GN; j = t % CN; i = t / CN + 1; }
        else               { k = r % CN; t = r / CN; j = t % GN + 1; i = t / GN + 1; }
        const float flin = (float)((i * CN + j) * CN + k);   // cell id, exact (<2^24)
        nts4(quads + seg * QSEG + r, (f4){flin + d0, flin + d1, flin + d2, flin + d3});
    }
}

// ========================= verts role (verts/vmask/qmask) =================
__device__ __forceinline__ void verts_body(unsigned vb, const float* __restrict__ g,
                                           float* __restrict__ out) {
    __shared__ __align__(16) float vlds[256 * 3];
    __shared__ float qAl[256], qBl[256], qCl[256];

    const int tid = threadIdx.x;
    const size_t lin0 = (size_t)vb * 256;
    const size_t lin = lin0 + tid;
    const bool valid = lin < NV;
    const int linI = valid ? (int)lin : (int)(NV - 1);
    const int k = linI % CN;
    const int t2 = linI / CN;
    const int j = t2 % CN;
    const int i = t2 / CN;

    // ---- uniform qmask windows from block's first/last lin ----
    const int L0 = (int)lin0;
    const int L1 = (int)((lin0 + 255 < NV) ? (lin0 + 255) : (NV - 1));
    const int k0 = L0 % CN, u0 = L0 / CN, j0 = u0 % CN, i0 = u0 / CN;
    const int k1 = L1 % CN, u1 = L1 / CN, j1 = u1 % CN, i1 = u1 / CN;

    int rminA, rmaxA, rminB, rmaxB, rminC, rmaxC;
    // segment A: valid j<192 && k<192; r = (i*192+j)*192+k
    { int a = i0, bb = j0, c = k0;
      if (bb == GN) { a++; bb = 0; c = 0; }
      else if (c == GN) { bb++; c = 0; if (bb == GN) { a++; bb = 0; } }
      rminA = (a * GN + bb) * GN + c; }
    { int a = i1, bb = j1, c = k1;
      if (bb == GN) { bb = GN - 1; c = GN - 1; }
      else if (c == GN) { c = GN - 1; }
      rmaxA = (a * GN + bb) * GN + c; }
    // segment B: valid i>=1 && k<192; r = ((i-1)*193+j)*192+k
    { int a = i0, bb = j0, c = k0;
      if (a == 0) { a = 1; bb = 0; c = 0; }
      else if (c == GN) { bb++; c = 0; if (bb == CN) { bb = 0; a++; } }
      rminB = ((a - 1) * CN + bb) * GN + c; }
    { int a = i1, bb = j1, c = k1;
      if (a == 0) rmaxB = -1;
      else { if (c == GN) c = GN - 1; rmaxB = ((a - 1) * CN + bb) * GN + c; } }
    // segment C: valid i>=1 && j>=1; r = ((i-1)*192+(j-1))*193+k
    { int a = i0, bb = j0, c = k0;
      if (a == 0) { a = 1; bb = 1; c = 0; }
      else if (bb == 0) { bb = 1; c = 0; }
      rminC = ((a - 1) * GN + (bb - 1)) * CN + c; }
    { int a = i1, bb = j1, c = k1;
      if (a == 0) rmaxC = -1;
      else if (bb == 0) { a--; rmaxC = (a == 0) ? -1 : ((a - 1) * GN + (GN - 1)) * CN + (CN - 1); }
      else rmaxC = ((a - 1) * GN + (bb - 1)) * CN + c; }
    int cntA = rmaxA - rminA + 1; if (cntA < 0) cntA = 0;
    int cntB = rmaxB - rminB + 1; if (cntB < 0) cntB = 0;
    int cntC = rmaxC - rminC + 1; if (cntC < 0) cntC = 0;

    // ---- branchless clamped corner loads (pad = iso+1 = 1.0) ----
    const int xm = (i >= 1) ? i - 1 : 0;
    const int xp = (i <= GN - 1) ? i : GN - 1;
    const int ym = (j >= 1) ? j - 1 : 0;
    const int yp = (j <= GN - 1) ? j : GN - 1;
    const int zm = (k >= 1) ? k - 1 : 0;
    const int zp = (k <= GN - 1) ? k : GN - 1;
    const bool xv0 = (i >= 1), xv1 = (i <= GN - 1);
    const bool yv0 = (j >= 1), yv1 = (j <= GN - 1);
    const bool zv0 = (k >= 1), zv1 = (k <= GN - 1);

    const float* b00 = g + ((size_t)xm * GN + ym) * GN;
    const float* b01 = g + ((size_t)xm * GN + yp) * GN;
    const float* b10 = g + ((size_t)xp * GN + ym) * GN;
    const float* b11 = g + ((size_t)xp * GN + yp) * GN;

    const float v000 = (xv0 & yv0 & zv0) ? b00[zm] : 1.0f;
    const float v001 = (xv0 & yv0 & zv1) ? b00[zp] : 1.0f;
    const float v010 = (xv0 & yv1 & zv0) ? b01[zm] : 1.0f;
    const float v011 = (xv0 & yv1 & zv1) ? b01[zp] : 1.0f;
    const float v100 = (xv1 & yv0 & zv0) ? b10[zm] : 1.0f;
    const float v101 = (xv1 & yv0 & zv1) ? b10[zp] : 1.0f;
    const float v110 = (xv1 & yv1 & zv0) ? b11[zm] : 1.0f;
    const float v111 = (xv1 & yv1 & zv1) ? b11[zp] : 1.0f;

    // ---- dual vertex: branchless 12-edge accumulation, Newton-refined rcp ----
    float sx = 0.f, sy = 0.f, sz = 0.f, cf = 0.f;
    auto acc = [&](float vA, float vB, int axis, float o1, float o2) {
        const bool cr = (vA < 0.f) != (vB < 0.f);
        const float m = cr ? 1.0f : 0.0f;
        const float d = cr ? (vB - vA) : 1.0f;      // safe operand (no inf/NaN)
        float r = __builtin_amdgcn_rcpf(d);
        r = r * (2.0f - d * r);                      // 1 Newton step
        const float t = cr ? (-vA * r) : 0.0f;
        if (axis == 0)      { sx += t;      sy += m * o1; sz += m * o2; }
        else if (axis == 1) { sx += m * o1; sy += t;      sz += m * o2; }
        else                { sx += m * o1; sy += m * o2; sz += t;      }
        cf += m;
    };
    acc(v000, v100, 0, 0.f, 0.f);
    acc(v010, v110, 0, 1.f, 0.f);
    acc(v001, v101, 0, 0.f, 1.f);
    acc(v011, v111, 0, 1.f, 1.f);
    acc(v000, v010, 1, 0.f, 0.f);
    acc(v100, v110, 1, 1.f, 0.f);
    acc(v001, v011, 1, 0.f, 1.f);
    acc(v101, v111, 1, 1.f, 1.f);
    acc(v000, v001, 2, 0.f, 0.f);
    acc(v100, v101, 2, 1.f, 0.f);
    acc(v010, v011, 2, 0.f, 1.f);
    acc(v110, v111, 2, 1.f, 1.f);

    const float cfm = fmaxf(cf, 1.0f);
    float rc = __builtin_amdgcn_rcpf(cfm);
    rc = rc * (2.0f - cfm * rc);
    const float inv191 = 1.0f / 191.0f;
    vlds[tid * 3 + 0] = ((float)i + sx * rc - 1.0f) * inv191;
    vlds[tid * 3 + 1] = ((float)j + sy * rc - 1.0f) * inv191;
    vlds[tid * 3 + 2] = ((float)k + sz * rc - 1.0f) * inv191;

    // vmask: per-thread dword, naturally contiguous
    if (valid) nts(out + OFF_VMASK + lin, (cf > 0.f) ? 1.0f : 0.0f);

    // qmask values -> LDS at window slot
    if (valid) {
        if (j < GN && k < GN)
            qAl[(i * GN + j) * GN + k - rminA] = ((v011 < 0.f) != (v111 < 0.f)) ? 1.0f : 0.0f;
        if (i >= 1 && k < GN)
            qBl[((i - 1) * CN + j) * GN + k - rminB] = ((v001 < 0.f) != (v011 < 0.f)) ? 1.0f : 0.0f;
        if (i >= 1 && j >= 1)
            qCl[((i - 1) * GN + (j - 1)) * CN + k - rminC] = ((v000 < 0.f) != (v001 < 0.f)) ? 1.0f : 0.0f;
    }
    __syncthreads();

    // ---- cooperative coalesced stores ----
    const int nvalid = L1 - L0 + 1;
    const int nfl = 3 * nvalid;
    const int nf4 = nfl >> 2;
    if (tid < nf4)
        nts4((f4*)(out + lin0 * 3) + tid, ((const f4*)vlds)[tid]);   // 16B-aligned
    if (tid == nf4)
        for (int rr = nf4 * 4; rr < nfl; ++rr) nts(out + lin0 * 3 + rr, vlds[rr]);

    if (tid < cntA) nts(out + OFF_QMASK + (size_t)rminA + tid, qAl[tid]);
    if (tid < cntB) nts(out + OFF_QMASK + QSEG + (size_t)rminB + tid, qBl[tid]);
    if (tid < cntC) nts(out + OFF_QMASK + 2 * QSEG + (size_t)rminC + tid, qCl[tid]);
}

// ========================= merged dispatch ================================
// Interleave roles so every CU hosts both: groups of 7 blocks = 3 quads + 4
// verts (matches the 20844:28083 ratio). quads' pure-store stream fills the
// bandwidth the latency-bound verts phase leaves idle. Role is block-uniform
// (no divergence; __syncthreads only on the verts path, whole block together).
#define NGROUPS 7021u   // max(ceil(20844/3), ceil(28083/4))

__global__ __launch_bounds__(256) void dmc_all(const float* __restrict__ g,
                                               float* __restrict__ out) {
    const unsigned bid = blockIdx.x;
    const unsigned grp = bid / 7u;
    const unsigned slot = bid - grp * 7u;
    if (slot < 3u) {
        const unsigned qb = grp * 3u + slot;
        if (qb < NQB) quads_body(qb, out);
    } else {
        const unsigned vb = grp * 4u + (slot - 3u);
        if (vb < NBV) verts_body(vb, g, out);
    }
}

extern "C" void kernel_launch(void* const* d_in, const int* in_sizes, int n_in,
                              void* d_out, int out_size, void* d_ws, size_t ws_size,
                              hipStream_t stream) {
    const float* g = (const float*)d_in[0];
    float* out = (float*)d_out;
    dmc_all<<<dim3(NGROUPS * 7u), dim3(256), 0, stream>>>(g, out);
}